// Round 2
// baseline (543.168 us; speedup 1.0000x reference)
//
#include <hip/hip_runtime.h>

#define N_FEAT   512
#define N_PAIRS  130816   // 512*511/2, divisible by 256
#define BROWS    4
#define VEC      4
#define TPB      256
#define PAIRS_PER_BLOCK (TPB * VEC)   // 1024

__global__ __launch_bounds__(TPB) void widelayer_kernel(
    const float* __restrict__ x,
    const float* __restrict__ w,
    float* __restrict__ out)
{
    __shared__ float xs[BROWS][N_FEAT];
    const int tid   = threadIdx.x;
    const int rbase = blockIdx.y * BROWS;

    // Stage BROWS rows of x (BROWS*512 floats = 512 float4) into LDS, 2 per thread.
    const float4* xv  = (const float4*)(x + (long long)rbase * N_FEAT);
    float4*       xsv = (float4*)&xs[0][0];
#pragma unroll
    for (int k = 0; k < (BROWS * N_FEAT / 4) / TPB; ++k)
        xsv[tid + k * TPB] = xv[tid + k * TPB];
    __syncthreads();

    const int base = blockIdx.x * PAIRS_PER_BLOCK;

    // Block-strided pair assignment: thread handles p = base + tid + k*TPB.
    // For fixed k, adjacent lanes have adjacent p -> adjacent j -> stride-1 LDS
    // reads (<=2 lanes/bank: conflict-free), xi read is a wave broadcast.
    bool  vk[VEC];
    int   ii[VEC], jj[VEC];
    float wk[VEC];
#pragma unroll
    for (int k = 0; k < VEC; ++k) {
        vk[k] = (base + k * TPB) < N_PAIRS;   // slice-uniform (N_PAIRS%TPB==0)
        int p = vk[k] ? (base + k * TPB + tid) : 0;

        // Closed-form p -> (i, j): f(i) = i*(1023-i)/2 pairs precede row i.
        // disc = 1023^2 - 8p <= 2^20: exact in fp32; fixups absorb sqrt rounding.
        float disc = (float)(1046529 - 8 * p);
        int i = (int)((1023.0f - sqrtf(disc)) * 0.5f);
        if (i < 0)   i = 0;
        if (i > 510) i = 510;
        while ((i + 1) * (1023 - (i + 1)) / 2 <= p && i < 510) ++i;
        while (i * (1023 - i) / 2 > p) --i;
        ii[k] = i;
        jj[k] = i + 1 + (p - i * (1023 - i) / 2);
        wk[k] = w[p];                                    // coalesced dword load
    }

#pragma unroll
    for (int r = 0; r < BROWS; ++r) {
        const float* xr = xs[r];
        float* orow = out + (long long)(rbase + r) * N_PAIRS + base + tid;
#pragma unroll
        for (int k = 0; k < VEC; ++k) {
            if (vk[k]) {
                // 64 lanes * 4B = contiguous 256B-aligned wave store; NT keeps
                // the 536MB write stream from evicting the L2-resident w.
                __builtin_nontemporal_store(xr[ii[k]] * xr[jj[k]] * wk[k],
                                            orow + k * TPB);
            }
        }
    }
}

extern "C" void kernel_launch(void* const* d_in, const int* in_sizes, int n_in,
                              void* d_out, int out_size, void* d_ws, size_t ws_size,
                              hipStream_t stream) {
    const float* x = (const float*)d_in[0];
    const float* w = (const float*)d_in[1];
    float* out = (float*)d_out;

    const int batch = in_sizes[0] / N_FEAT;   // 1024
    dim3 grid((N_PAIRS + PAIRS_PER_BLOCK - 1) / PAIRS_PER_BLOCK, batch / BROWS);
    widelayer_kernel<<<grid, TPB, 0, stream>>>(x, w, out);
}